// Round 12
// baseline (207.136 us; speedup 1.0000x reference)
//
#include <hip/hip_runtime.h>
#include <stdint.h>

#define DEV __device__ __forceinline__

typedef __attribute__((ext_vector_type(4))) float f32x4;
typedef __attribute__((ext_vector_type(8))) __bf16 bf16x8;
typedef __attribute__((ext_vector_type(8))) unsigned short ushort8;
typedef __attribute__((ext_vector_type(4))) unsigned short u16x4;
typedef __attribute__((ext_vector_type(4))) int i32x4;
typedef __attribute__((ext_vector_type(2))) unsigned int u32x2;

DEV unsigned short f2bf(float f) {
    union { float f; unsigned int u; } v; v.f = f;
    unsigned int r = v.u + 0x7FFFu + ((v.u >> 16) & 1u);
    return (unsigned short)(r >> 16);
}
DEV float bf2f(unsigned short u) {
    union { unsigned int u; float f; } v; v.u = ((unsigned int)u) << 16;
    return v.f;
}
DEV unsigned int cvt_pk_bf16(float lo, float hi) {
    unsigned int r;
    asm("v_cvt_pk_bf16_f32 %0, %1, %2" : "=v"(r) : "v"(lo), "v"(hi));
    return r;
}
// XOR-swizzle a linear LDS byte offset (128B rows): byte ^= ((row&7)<<4)
DEV int swz(int o) { return o ^ ((o >> 3) & 0x70); }

DEV void gload_lds16(const void* gptr, void* lptr) {
    __builtin_amdgcn_global_load_lds(
        (const __attribute__((address_space(1))) unsigned int*)gptr,
        (__attribute__((address_space(3))) unsigned int*)lptr, 16, 0, 0);
}

// ---------------- fused prep: fp32->bf16 convert of q,k,v + W transpose ----------
// grid (2304,1,3): bx<2048 -> convert slice; bx>=2048 -> 64x64 W-transpose tile.
__global__ void k_prep(const float* __restrict__ q, const float* __restrict__ k,
                       const float* __restrict__ v, const float* __restrict__ Wq,
                       const float* __restrict__ Wk, const float* __restrict__ Wv,
                       unsigned short* __restrict__ qb, unsigned short* __restrict__ kb,
                       unsigned short* __restrict__ vb, unsigned short* __restrict__ wt) {
    __shared__ float tile[64 * 65];
    const int z = blockIdx.z;
    const int bx = blockIdx.x;
    const int t = threadIdx.x;
    if (bx < 2048) {
        const float* src = z == 0 ? q : (z == 1 ? k : v);
        unsigned short* dst = z == 0 ? qb : (z == 1 ? kb : vb);
        const size_t idx = ((size_t)bx * 256 + t) * 8;
        f32x4 a = *(const f32x4*)(src + idx);
        f32x4 b = *(const f32x4*)(src + idx + 4);
        ushort8 o;
        o[0] = f2bf(a[0]); o[1] = f2bf(a[1]); o[2] = f2bf(a[2]); o[3] = f2bf(a[3]);
        o[4] = f2bf(b[0]); o[5] = f2bf(b[1]); o[6] = f2bf(b[2]); o[7] = f2bf(b[3]);
        *(ushort8*)(dst + idx) = o;
    } else {
        const int b = bx - 2048;                    // 256 blocks = 16 k-tiles x 16 n-tiles
        const float* W = z == 0 ? Wq : (z == 1 ? Wk : Wv);
        unsigned short* dst = wt + (size_t)z * 1048576;
        const int k0 = (b & 15) * 64, n0 = (b >> 4) * 64;
#pragma unroll
        for (int i = 0; i < 4; i++) {
            const int idx = i * 256 + t;
            const int row = idx >> 4, c4 = (idx & 15) * 4;
            f32x4 val = *(const f32x4*)(W + (size_t)(k0 + row) * 1024 + n0 + c4);
#pragma unroll
            for (int j = 0; j < 4; j++) tile[row * 65 + c4 + j] = val[j];
        }
        __syncthreads();
#pragma unroll
        for (int i = 0; i < 2; i++) {
            const int idx = i * 256 + t;
            const int nrow = idx >> 3, c8 = (idx & 7) * 8;
            ushort8 o;
#pragma unroll
            for (int j = 0; j < 8; j++) o[j] = f2bf(tile[(c8 + j) * 65 + nrow]);
            *(ushort8*)(dst + (size_t)(n0 + nrow) * 1024 + k0 + c8) = o;
        }
    }
}

// ---------------- projection GEMM: C = A(4096x1024) * Wt^T + bias ----------------
// Depth-2 prefetch, COUNTED vmcnt (T4): tiles kt and kt+1 in flight; wait
// vmcnt(8) = tile kt landed. Bijective XCD swizzle (T1).
// z==0/1 -> qh/kh [hb][s][d]; z==2 -> vt [hb][d][s] + fused vmean atomics.
__global__ __launch_bounds__(256) void k_proj(
    const unsigned short* __restrict__ qb, const unsigned short* __restrict__ kb,
    const unsigned short* __restrict__ vb, const unsigned short* __restrict__ wt,
    const float* __restrict__ bq, const float* __restrict__ bk, const float* __restrict__ bv,
    unsigned short* __restrict__ qh, unsigned short* __restrict__ kh,
    unsigned short* __restrict__ vt, float* __restrict__ vmean) {
    const int z = blockIdx.z;
    const unsigned short* A  = z == 0 ? qb : (z == 1 ? kb : vb);
    const unsigned short* Bt = wt + (size_t)z * 1048576;
    const float* bias = z == 0 ? bq : (z == 1 ? bk : bv);
    // z==0: fold 1/sqrt(dh) * log2(e) so attention softmax runs in exp2 domain
    const float scale = z == 0 ? 0.18033688011112042f : 1.0f;

    __shared__ unsigned short sA[2][128 * 64];
    __shared__ unsigned short sB[2][128 * 64];

    const int tid = threadIdx.x;
    const int w = tid >> 6, lane = tid & 63;
    const int c = lane & 15, gq = lane >> 4;
    const int wrow = w >> 1, wcol = w & 1;
    // XCD-aware swizzle (nwg=256 per z, divisible by 8): XCD x owns wg [x*32,(x+1)*32)
    const int orig = blockIdx.x;
    const int wg = (orig & 7) * 32 + (orig >> 3);
    const int n0 = (wg & 7) * 128;          // 8 n-tiles
    const int m0 = (wg >> 3) * 128;         // 32 m-tiles; chunk = 4 consecutive m
    const int lr = lane >> 3;
    const int lcs = ((lane & 7) ^ (lane >> 3)) * 8;

    f32x4 acc[4][4] = {};

    auto stageAB = [&](int kt, int buf) {
        const int kb0 = kt * 64;
#pragma unroll
        for (int i = 0; i < 4; i++) {
            const int rbase = w * 32 + i * 8;
            gload_lds16(A  + (size_t)(m0 + rbase + lr) * 1024 + kb0 + lcs,
                        (char*)sA[buf] + rbase * 128);
            gload_lds16(Bt + (size_t)(n0 + rbase + lr) * 1024 + kb0 + lcs,
                        (char*)sB[buf] + rbase * 128);
        }
    };

    stageAB(0, 0);
    stageAB(1, 1);                                    // 16 loads/wave in flight

    for (int kt = 0; kt < 16; kt++) {
        const int cur = kt & 1;
        if (kt < 15) asm volatile("s_waitcnt vmcnt(8)" ::: "memory");  // tile kt landed
        else         asm volatile("s_waitcnt vmcnt(0)" ::: "memory");
        __builtin_amdgcn_s_barrier();
        __builtin_amdgcn_sched_barrier(0);
#pragma unroll
        for (int kk = 0; kk < 2; kk++) {
            bf16x8 af[4], bfr[4];
#pragma unroll
            for (int i = 0; i < 4; i++) {
                af[i]  = *(const bf16x8*)((char*)sA[cur] +
                          swz((wrow * 64 + i * 16 + c) * 128 + kk * 64 + gq * 16));
                bfr[i] = *(const bf16x8*)((char*)sB[cur] +
                          swz((wcol * 64 + i * 16 + c) * 128 + kk * 64 + gq * 16));
            }
#pragma unroll
            for (int mi = 0; mi < 4; mi++)
#pragma unroll
                for (int ni = 0; ni < 4; ni++)
                    acc[mi][ni] = __builtin_amdgcn_mfma_f32_16x16x32_bf16(
                        af[mi], bfr[ni], acc[mi][ni], 0, 0, 0);
        }
        __builtin_amdgcn_sched_barrier(0);
        __builtin_amdgcn_s_barrier();        // all waves done reading buf[cur]
        if (kt + 2 < 16) stageAB(kt + 2, cur);   // refill freed buffer, stays in flight
    }

    float bvals[4];
#pragma unroll
    for (int ni = 0; ni < 4; ni++) bvals[ni] = bias[n0 + wcol * 64 + ni * 16 + c];

    if (z < 2) {
        unsigned short* outp = z == 0 ? qh : kh;
#pragma unroll
        for (int mi = 0; mi < 4; mi++)
#pragma unroll
            for (int ni = 0; ni < 4; ni++) {
                const int n = n0 + wcol * 64 + ni * 16 + c;
                const int head = n >> 6, d = n & 63;
#pragma unroll
                for (int r = 0; r < 4; r++) {
                    const int m = m0 + wrow * 64 + mi * 16 + gq * 4 + r;
                    const int bb = m >> 10, s = m & 1023;
                    const float val = (acc[mi][ni][r] + bvals[ni]) * scale;
                    outp[(size_t)((head << 2) + bb) * 65536 + (size_t)s * 64 + d] = f2bf(val);
                }
            }
    } else {
        // transposed write: vt [hb][d][s]; r=0..3 -> 4 consecutive s -> u16x4 store
        const int bb = m0 >> 10;                // 128 | 1024 -> constant per block
#pragma unroll
        for (int mi = 0; mi < 4; mi++)
#pragma unroll
            for (int ni = 0; ni < 4; ni++) {
                const int n = n0 + wcol * 64 + ni * 16 + c;
                const int head = n >> 6, d = n & 63;
                const int mbase = m0 + wrow * 64 + mi * 16 + gq * 4;
                const int sloc = mbase & 1023;
                u16x4 o;
#pragma unroll
                for (int r = 0; r < 4; r++) o[r] = f2bf(acc[mi][ni][r] + bvals[ni]);
                *(u16x4*)(vt + (size_t)((head << 2) + bb) * 65536 +
                          (size_t)d * 1024 + sloc) = o;
            }
        // fused vmean: mean_s(V Wv + bv) by linearity -- this block covers 128 of
        // 1024 s-rows for its (b, 2 heads); thread owns 16 rows per column.
#pragma unroll
        for (int ni = 0; ni < 4; ni++) {
            const int n = n0 + wcol * 64 + ni * 16 + c;
            const int head = n >> 6, d = n & 63;
            float ps = 16.0f * bvals[ni];
#pragma unroll
            for (int mi = 0; mi < 4; mi++)
#pragma unroll
                for (int r = 0; r < 4; r++) ps += acc[mi][ni][r];
            atomicAdd(&vmean[((head << 2) + bb) * 64 + d], ps * (1.0f / 1024.0f));
        }
    }
}

// ---------------- flash attention, split-KV, swapped QK^T + LDS staging ----------
// grid (40, 64): idx -> (qt, chunk); chunk covers KV tiles [4c, min(4c+4, qt+1)).
// K/V double-buffered via global_load_lds (pre-swizzled source), counted vmcnt(4).
// In-register row softmax: lane c owns q=q0+c (S^T = mfma(K,Q)), 2 shfl per tile.
// Defer-max (T13, THR=8 log2); setprio(1) around MFMA clusters (T5).
__global__ __launch_bounds__(256) void k_attn(
    const unsigned short* __restrict__ qh, const unsigned short* __restrict__ kh,
    const unsigned short* __restrict__ vt, const int* __restrict__ mask,
    const float* __restrict__ vmean, float* __restrict__ out,
    char* __restrict__ part) {
    __shared__ unsigned short sK[2][64 * 64];
    __shared__ unsigned short sV[2][64 * 64];   // V^T tiles: [d][kv]
    __shared__ unsigned short sP[4 * 16 * 64];  // per-wave 16q x 64kv P tile

    const int idx = blockIdx.x, hb = blockIdx.y;
    int qt, ch, nch;
    if (idx < 4)       { qt = idx;                 ch = 0;             nch = 1; }
    else if (idx < 12) { qt = 4 + ((idx - 4) >> 1);  ch = (idx - 4) & 1;  nch = 2; }
    else if (idx < 24) { int r = idx - 12; qt = 8 + r / 3; ch = r % 3;   nch = 3; }
    else               { qt = 12 + ((idx - 24) >> 2); ch = (idx - 24) & 3; nch = 4; }
    const int t0 = ch * 4;
    const int t1 = min(t0 + 4, qt + 1);

    const int tid = threadIdx.x;
    const int w = tid >> 6, lane = tid & 63;
    const int c = lane & 15, g = lane >> 4, g4 = g * 4;
    const int q0 = qt * 64 + w * 16;
    const int qg = q0 + c;                        // this lane's q row
    const size_t hboff = (size_t)hb * 65536;
    const int* mp = mask + hb * 1024;
    unsigned short* pw = sP + w * 1024;

    bf16x8 aq[2];
#pragma unroll
    for (int kk = 0; kk < 2; kk++)
        aq[kk] = *(const bf16x8*)(qh + hboff + (size_t)qg * 64 + kk * 32 + g * 8);

    f32x4 oacc[4] = {};
    float lsum = 0.f, mrow = -1e30f;

    const int srow = tid >> 3, sch = tid & 7;
    const int ssc = (sch ^ (srow & 7)) * 8;          // pre-swizzled source col

    auto stage = [&](int t, int buf) {
        const int kv0 = t * 64;
#pragma unroll
        for (int i = 0; i < 2; i++) {
            const int row = i * 32 + srow;
            gload_lds16(kh + hboff + (size_t)(kv0 + row) * 64 + ssc,
                        (char*)sK[buf] + row * 128 + sch * 16);
        }
#pragma unroll
        for (int i = 0; i < 2; i++) {
            const int row = i * 32 + srow;               // row = d
            gload_lds16(vt + hboff + (size_t)row * 1024 + kv0 + ssc,
                        (char*)sV[buf] + row * 128 + sch * 16);
        }
    };

    stage(t0, 0);
    for (int t = t0; t < t1; t++) {
        const int cur = (t - t0) & 1;
        if (t + 1 < t1) {
            stage(t + 1, cur ^ 1);
            asm volatile("s_waitcnt vmcnt(4)" ::: "memory");   // tile t's 4 loads done
        } else {
            asm volatile("s_waitcnt vmcnt(0)" ::: "memory");
        }
        __builtin_amdgcn_s_barrier();
        __builtin_amdgcn_sched_barrier(0);

        const int kv0 = t * 64;
        const bool diag = (t == qt);
        const unsigned short* sKc = sK[cur];
        const unsigned short* sVc = sV[cur];

        // S^T = K Q^T : sacc[ns][r] = S[kv0+ns*16+g4+r][q0+c]
        f32x4 sacc[4] = {};
        __builtin_amdgcn_s_setprio(1);
#pragma unroll
        for (int ns = 0; ns < 4; ns++)
#pragma unroll
            for (int kk = 0; kk < 2; kk++) {
                const bf16x8 bk = *(const bf16x8*)((char*)sKc +
                                    swz((ns * 16 + c) * 128 + kk * 64 + g * 16));
                sacc[ns] = __builtin_amdgcn_mfma_f32_16x16x32_bf16(bk, aq[kk], sacc[ns], 0, 0, 0);
            }
        __builtin_amdgcn_s_setprio(0);

        // mask + causal (per-lane registers)
        float sv[4][4];
        float mx = -1e30f;
#pragma unroll
        for (int ns = 0; ns < 4; ns++) {
            const i32x4 mm = *(const i32x4*)(mp + kv0 + ns * 16 + g4);
#pragma unroll
            for (int r = 0; r < 4; r++) {
                float s = (mm[r] != 0) ? sacc[ns][r] : -1e30f;
                if (diag) s = (kv0 + ns * 16 + g4 + r <= qg) ? s : -1e30f;
                sv[ns][r] = s;
                mx = fmaxf(mx, s);
            }
        }
        // row reduce across g-groups (lanes c, c+16, c+32, c+48)
        mx = fmaxf(mx, __shfl_xor(mx, 16, 64));
        mx = fmaxf(mx, __shfl_xor(mx, 32, 64));

        // defer-max: only rescale when some row's max grew past mrow + 8
        if (!__all(mx - mrow <= 8.0f)) {
            const float mnew = fmaxf(mrow, mx);
            const float alpha = exp2f(mrow - mnew);
            mrow = mnew;
            lsum *= alpha;
            float av[4];
#pragma unroll
            for (int r = 0; r < 4; r++) av[r] = __shfl(alpha, g4 + r, 16);
#pragma unroll
            for (int nd = 0; nd < 4; nd++)
#pragma unroll
                for (int r = 0; r < 4; r++) oacc[nd][r] *= av[r];
        }

        float rs = 0.f;
        u32x2 pk[4];
#pragma unroll
        for (int ns = 0; ns < 4; ns++) {
            const float e0 = exp2f(sv[ns][0] - mrow);
            const float e1 = exp2f(sv[ns][1] - mrow);
            const float e2 = exp2f(sv[ns][2] - mrow);
            const float e3 = exp2f(sv[ns][3] - mrow);
            rs += (e0 + e1) + (e2 + e3);
            pk[ns][0] = cvt_pk_bf16(e0, e1);
            pk[ns][1] = cvt_pk_bf16(e2, e3);
        }
        rs += __shfl_xor(rs, 16, 64);
        rs += __shfl_xor(rs, 32, 64);
        lsum += rs;

        // write P^T fragment -> sP[q=c][kv], 8B per ns
#pragma unroll
        for (int ns = 0; ns < 4; ns++)
            *(u32x2*)((char*)pw + swz(c * 128 + (ns * 16 + g4) * 2)) = pk[ns];

        asm volatile("s_waitcnt lgkmcnt(0)" ::: "memory");
        // O += P V  (A = P rows q=c from sP, B = V^T frags from sV)
        __builtin_amdgcn_s_setprio(1);
#pragma unroll
        for (int ks = 0; ks < 2; ks++) {
            const bf16x8 ap = *(const bf16x8*)((char*)pw + swz(c * 128 + ks * 64 + g * 16));
#pragma unroll
            for (int nd = 0; nd < 4; nd++) {
                const bf16x8 bvv = *(const bf16x8*)((char*)sVc +
                                     swz((nd * 16 + c) * 128 + ks * 64 + g * 16));
                oacc[nd] = __builtin_amdgcn_mfma_f32_16x16x32_bf16(ap, bvv, oacc[nd], 0, 0, 0);
            }
        }
        __builtin_amdgcn_s_setprio(0);
        __builtin_amdgcn_sched_barrier(0);
        __builtin_amdgcn_s_barrier();      // LDS reads done before next stage overwrites
        __builtin_amdgcn_sched_barrier(0);
    }

    if (nch == 1) {
        const int bidx = hb & 3, head = hb >> 2;
        float lf[4], mf[4];
#pragma unroll
        for (int r = 0; r < 4; r++) {
            lf[r] = __shfl(lsum, g4 + r, 16);
            mf[r] = __shfl(mrow, g4 + r, 16);
        }
#pragma unroll
        for (int nd = 0; nd < 4; nd++)
#pragma unroll
            for (int r = 0; r < 4; r++) {
                const int s = q0 + g4 + r;
                const int dcol = nd * 16 + c;
                const float val = (mf[r] < -5e29f) ? vmean[hb * 64 + dcol]
                                                   : oacc[nd][r] / lf[r];
                out[(size_t)bidx * 1048576 + (size_t)s * 1024 + head * 64 + dcol] = val;
            }
    } else {
        // partial: bf16 O~ [64][64] + f32 m[64] + f32 l[64]  (slot = idx-4)
        char* sp = part + ((size_t)hb * 36 + (idx - 4)) * 8704;
        unsigned short* op = (unsigned short*)sp;
#pragma unroll
        for (int nd = 0; nd < 4; nd++)
#pragma unroll
            for (int r = 0; r < 4; r++)
                op[(w * 16 + g4 + r) * 64 + nd * 16 + c] = f2bf(oacc[nd][r]);
        if (g == 0) {   // lanes 0-15 hold m/l for q = w*16 + c
            float* mo = (float*)(sp + 8192);
            float* lo = (float*)(sp + 8448);
            mo[w * 16 + c] = mrow;
            lo[w * 16 + c] = lsum;
        }
    }
}

// ---------------- combine partials for qt >= 4 ----------------
__global__ __launch_bounds__(256) void k_combine(
    const char* __restrict__ part, const float* __restrict__ vmean,
    float* __restrict__ out) {
    const int qt = 4 + blockIdx.x, hb = blockIdx.y;
    int nch, base;
    if (qt < 8)       { nch = 2; base = (qt - 4) * 2; }
    else if (qt < 12) { nch = 3; base = 8 + (qt - 8) * 3; }
    else              { nch = 4; base = 20 + (qt - 12) * 4; }
    const int t = threadIdx.x;
    const int row = t >> 2, d0 = (t & 3) * 16;
    const char* sp0 = part + ((size_t)hb * 36 + base) * 8704;

    float mi[4], li[4];
    float m = -1e30f;
#pragma unroll
    for (int i = 0; i < 4; i++)
        if (i < nch) {
            const char* sp = sp0 + (size_t)i * 8704;
            mi[i] = ((const float*)(sp + 8192))[row];
            li[i] = ((const float*)(sp + 8448))[row];
            m = fmaxf(m, mi[i]);
        }
    float L = 0.f;
    float o[16];
#pragma unroll
    for (int j = 0; j < 16; j++) o[j] = 0.f;
#pragma unroll
    for (int i = 0; i < 4; i++)
        if (i < nch) {
            const float wgt = exp2f(mi[i] - m);
            L += wgt * li[i];
            const unsigned short* op =
                (const unsigned short*)(sp0 + (size_t)i * 8704) + row * 64 + d0;
            ushort8 a = *(const ushort8*)op;
            ushort8 b = *(const ushort8*)(op + 8);
#pragma unroll
            for (int j = 0; j < 8; j++) {
                o[j]     += wgt * bf2f(a[j]);
                o[8 + j] += wgt * bf2f(b[j]);
            }
        }
    const int bidx = hb & 3, head = hb >> 2;
    float* dst = out + (size_t)bidx * 1048576 + (size_t)(qt * 64 + row) * 1024 + head * 64 + d0;
    if (m > -5e29f) {   // fully-masked rows keep m=-1e30 -> uniform-softmax fallback
        const float inv = 1.0f / L;
#pragma unroll
        for (int j = 0; j < 16; j++) dst[j] = o[j] * inv;
    } else {
#pragma unroll
        for (int j = 0; j < 16; j++) dst[j] = vmean[hb * 64 + d0 + j];
    }
}

extern "C" void kernel_launch(void* const* d_in, const int* in_sizes, int n_in,
                              void* d_out, int out_size, void* d_ws, size_t ws_size,
                              hipStream_t stream) {
    const float* q  = (const float*)d_in[0];
    const float* k  = (const float*)d_in[1];
    const float* v  = (const float*)d_in[2];
    const int* mask = (const int*)d_in[3];
    const float* Wq = (const float*)d_in[4];
    const float* bq = (const float*)d_in[5];
    const float* Wk = (const float*)d_in[6];
    const float* bk = (const float*)d_in[7];
    const float* Wv = (const float*)d_in[8];
    const float* bv = (const float*)d_in[9];
    float* out = (float*)d_out;

    unsigned short* qb = (unsigned short*)d_ws;
    unsigned short* kb = qb + 4194304;
    unsigned short* vb = kb + 4194304;
    unsigned short* wt = vb + 4194304;     // 3 * 1048576
    unsigned short* qh = wt + 3 * 1048576;
    unsigned short* kh = qh + 4194304;
    unsigned short* vh = kh + 4194304;     // unused (kept for layout stability)
    unsigned short* vt = vh + 4194304;
    float* vmean = (float*)(vt + 4194304); // 64*64 floats
    char* part = (char*)qb;                // 20.1 MB, aliases qb/kb/vb (dead after k_proj)

    k_prep<<<dim3(2304, 1, 3), 256, 0, stream>>>(q, k, v, Wq, Wk, Wv, qb, kb, vb, wt);
    hipMemsetAsync(vmean, 0, 64 * 64 * sizeof(float), stream);
    k_proj<<<dim3(256, 1, 3), 256, 0, stream>>>(qb, kb, vb, wt, bq, bk, bv, qh, kh, vt, vmean);
    k_attn<<<dim3(40, 64), 256, 0, stream>>>(qh, kh, vt, mask, vmean, out, part);
    k_combine<<<dim3(12, 64), 256, 0, stream>>>(part, vmean, out);
}

// Round 13
// 200.069 us; speedup vs baseline: 1.0353x; 1.0353x over previous
//
#include <hip/hip_runtime.h>
#include <stdint.h>

#define DEV __device__ __forceinline__

typedef __attribute__((ext_vector_type(4))) float f32x4;
typedef __attribute__((ext_vector_type(8))) __bf16 bf16x8;
typedef __attribute__((ext_vector_type(8))) unsigned short ushort8;
typedef __attribute__((ext_vector_type(4))) unsigned short u16x4;
typedef __attribute__((ext_vector_type(4))) int i32x4;
typedef __attribute__((ext_vector_type(2))) unsigned int u32x2;

DEV unsigned short f2bf(float f) {
    union { float f; unsigned int u; } v; v.f = f;
    unsigned int r = v.u + 0x7FFFu + ((v.u >> 16) & 1u);
    return (unsigned short)(r >> 16);
}
DEV float bf2f(unsigned short u) {
    union { unsigned int u; float f; } v; v.u = ((unsigned int)u) << 16;
    return v.f;
}
DEV unsigned int cvt_pk_bf16(float lo, float hi) {
    unsigned int r;
    asm("v_cvt_pk_bf16_f32 %0, %1, %2" : "=v"(r) : "v"(lo), "v"(hi));
    return r;
}
// XOR-swizzle a linear LDS byte offset (128B rows): byte ^= ((row&7)<<4)
DEV int swz(int o) { return o ^ ((o >> 3) & 0x70); }

DEV void gload_lds16(const void* gptr, void* lptr) {
    __builtin_amdgcn_global_load_lds(
        (const __attribute__((address_space(1))) unsigned int*)gptr,
        (__attribute__((address_space(3))) unsigned int*)lptr, 16, 0, 0);
}

// ---------------- fused prep: fp32->bf16 convert of q,k,v + W transpose ----------
// grid (2304,1,3): bx<2048 -> convert slice; bx>=2048 -> 64x64 W-transpose tile.
__global__ void k_prep(const float* __restrict__ q, const float* __restrict__ k,
                       const float* __restrict__ v, const float* __restrict__ Wq,
                       const float* __restrict__ Wk, const float* __restrict__ Wv,
                       unsigned short* __restrict__ qb, unsigned short* __restrict__ kb,
                       unsigned short* __restrict__ vb, unsigned short* __restrict__ wt) {
    __shared__ float tile[64 * 65];
    const int z = blockIdx.z;
    const int bx = blockIdx.x;
    const int t = threadIdx.x;
    if (bx < 2048) {
        const float* src = z == 0 ? q : (z == 1 ? k : v);
        unsigned short* dst = z == 0 ? qb : (z == 1 ? kb : vb);
        const size_t idx = ((size_t)bx * 256 + t) * 8;
        f32x4 a = *(const f32x4*)(src + idx);
        f32x4 b = *(const f32x4*)(src + idx + 4);
        ushort8 o;
        o[0] = f2bf(a[0]); o[1] = f2bf(a[1]); o[2] = f2bf(a[2]); o[3] = f2bf(a[3]);
        o[4] = f2bf(b[0]); o[5] = f2bf(b[1]); o[6] = f2bf(b[2]); o[7] = f2bf(b[3]);
        *(ushort8*)(dst + idx) = o;
    } else {
        const int b = bx - 2048;                    // 256 blocks = 16 k-tiles x 16 n-tiles
        const float* W = z == 0 ? Wq : (z == 1 ? Wk : Wv);
        unsigned short* dst = wt + (size_t)z * 1048576;
        const int k0 = (b & 15) * 64, n0 = (b >> 4) * 64;
#pragma unroll
        for (int i = 0; i < 4; i++) {
            const int idx = i * 256 + t;
            const int row = idx >> 4, c4 = (idx & 15) * 4;
            f32x4 val = *(const f32x4*)(W + (size_t)(k0 + row) * 1024 + n0 + c4);
#pragma unroll
            for (int j = 0; j < 4; j++) tile[row * 65 + c4 + j] = val[j];
        }
        __syncthreads();
#pragma unroll
        for (int i = 0; i < 2; i++) {
            const int idx = i * 256 + t;
            const int nrow = idx >> 3, c8 = (idx & 7) * 8;
            ushort8 o;
#pragma unroll
            for (int j = 0; j < 8; j++) o[j] = f2bf(tile[(c8 + j) * 65 + nrow]);
            *(ushort8*)(dst + (size_t)(n0 + nrow) * 1024 + k0 + c8) = o;
        }
    }
}

// ---------------- projection GEMM: C = A(4096x1024) * Wt^T + bias ----------------
// 512 threads / 8 waves (2x4), wave tile 64x32 (acc[4][2]) -> 4 waves/SIMD for
// latency hiding. Depth-2 prefetch, counted vmcnt(4) (T4). Bijective XCD swizzle.
// z==0/1 -> qh/kh [hb][s][d]; z==2 -> vt [hb][d][s] (transposed write)
__global__ __launch_bounds__(512) void k_proj(
    const unsigned short* __restrict__ qb, const unsigned short* __restrict__ kb,
    const unsigned short* __restrict__ vb, const unsigned short* __restrict__ wt,
    const float* __restrict__ bq, const float* __restrict__ bk, const float* __restrict__ bv,
    unsigned short* __restrict__ qh, unsigned short* __restrict__ kh,
    unsigned short* __restrict__ vt) {
    const int z = blockIdx.z;
    const unsigned short* A  = z == 0 ? qb : (z == 1 ? kb : vb);
    const unsigned short* Bt = wt + (size_t)z * 1048576;
    const float* bias = z == 0 ? bq : (z == 1 ? bk : bv);
    // z==0: fold 1/sqrt(dh) * log2(e) so attention softmax runs in exp2 domain
    const float scale = z == 0 ? 0.18033688011112042f : 1.0f;

    __shared__ unsigned short sA[2][128 * 64];
    __shared__ unsigned short sB[2][128 * 64];

    const int tid = threadIdx.x;
    const int w = tid >> 6, lane = tid & 63;
    const int c = lane & 15, gq = lane >> 4;
    const int wrow = w >> 2, wcol = w & 3;          // 2x4 wave grid, 64x32 per wave
    // XCD-aware swizzle (nwg=256 per z, divisible by 8): XCD x owns wg [x*32,(x+1)*32)
    const int orig = blockIdx.x;
    const int wg = (orig & 7) * 32 + (orig >> 3);
    const int n0 = (wg & 7) * 128;          // 8 n-tiles
    const int m0 = (wg >> 3) * 128;         // 32 m-tiles; chunk = 4 consecutive m
    const int srow = tid >> 3, sch = tid & 7;       // staging: 64 rows x 8 chunks / pass
    const int lcs = ((sch ^ (srow & 7)) * 8);       // pre-swizzled source col (elems)

    f32x4 acc[4][2] = {};

    auto stageAB = [&](int kt, int buf) {
        const int kb0 = kt * 64;
#pragma unroll
        for (int i = 0; i < 2; i++) {
            const int row = i * 64 + srow;
            gload_lds16(A  + (size_t)(m0 + row) * 1024 + kb0 + lcs,
                        (char*)sA[buf] + row * 128);
            gload_lds16(Bt + (size_t)(n0 + row) * 1024 + kb0 + lcs,
                        (char*)sB[buf] + row * 128);
        }
    };

    stageAB(0, 0);
    stageAB(1, 1);                                    // 8 loads/thread in flight

    for (int kt = 0; kt < 16; kt++) {
        const int cur = kt & 1;
        if (kt < 15) asm volatile("s_waitcnt vmcnt(4)" ::: "memory");  // tile kt landed
        else         asm volatile("s_waitcnt vmcnt(0)" ::: "memory");
        __builtin_amdgcn_s_barrier();
        __builtin_amdgcn_sched_barrier(0);
#pragma unroll
        for (int kk = 0; kk < 2; kk++) {
            bf16x8 af[4], bfr[2];
#pragma unroll
            for (int i = 0; i < 4; i++)
                af[i]  = *(const bf16x8*)((char*)sA[cur] +
                          swz((wrow * 64 + i * 16 + c) * 128 + kk * 64 + gq * 16));
#pragma unroll
            for (int i = 0; i < 2; i++)
                bfr[i] = *(const bf16x8*)((char*)sB[cur] +
                          swz((wcol * 32 + i * 16 + c) * 128 + kk * 64 + gq * 16));
#pragma unroll
            for (int mi = 0; mi < 4; mi++)
#pragma unroll
                for (int ni = 0; ni < 2; ni++)
                    acc[mi][ni] = __builtin_amdgcn_mfma_f32_16x16x32_bf16(
                        af[mi], bfr[ni], acc[mi][ni], 0, 0, 0);
        }
        __builtin_amdgcn_sched_barrier(0);
        __builtin_amdgcn_s_barrier();        // all waves done reading buf[cur]
        if (kt + 2 < 16) stageAB(kt + 2, cur);   // refill freed buffer, stays in flight
    }

    float bvals[2];
#pragma unroll
    for (int ni = 0; ni < 2; ni++) bvals[ni] = bias[n0 + wcol * 32 + ni * 16 + c];

    if (z < 2) {
        unsigned short* outp = z == 0 ? qh : kh;
#pragma unroll
        for (int mi = 0; mi < 4; mi++)
#pragma unroll
            for (int ni = 0; ni < 2; ni++) {
                const int n = n0 + wcol * 32 + ni * 16 + c;
                const int head = n >> 6, d = n & 63;
#pragma unroll
                for (int r = 0; r < 4; r++) {
                    const int m = m0 + wrow * 64 + mi * 16 + gq * 4 + r;
                    const int bb = m >> 10, s = m & 1023;
                    const float val = (acc[mi][ni][r] + bvals[ni]) * scale;
                    outp[(size_t)((head << 2) + bb) * 65536 + (size_t)s * 64 + d] = f2bf(val);
                }
            }
    } else {
        // transposed write: vt [hb][d][s]; r=0..3 -> 4 consecutive s -> u16x4 store
#pragma unroll
        for (int mi = 0; mi < 4; mi++)
#pragma unroll
            for (int ni = 0; ni < 2; ni++) {
                const int n = n0 + wcol * 32 + ni * 16 + c;
                const int head = n >> 6, d = n & 63;
                const int mbase = m0 + wrow * 64 + mi * 16 + gq * 4;
                const int bb = mbase >> 10, sloc = mbase & 1023;
                u16x4 o;
#pragma unroll
                for (int r = 0; r < 4; r++) o[r] = f2bf(acc[mi][ni][r] + bvals[ni]);
                *(u16x4*)(vt + (size_t)((head << 2) + bb) * 65536 +
                          (size_t)d * 1024 + sloc) = o;
            }
    }
}

// ---------------- per-hb column mean of v (reads vt rows, coalesced) ----------------
__global__ void k_vmean(const unsigned short* __restrict__ vt, float* __restrict__ vmean) {
    __shared__ float red[256];
    const int hb = blockIdx.x, t = threadIdx.x;
    const int d = t >> 2, part = t & 3;
    const unsigned short* p = vt + (size_t)hb * 65536 + (size_t)d * 1024 + part * 256;
    float sum = 0.f;
#pragma unroll 4
    for (int i = 0; i < 32; i++) {
        ushort8 v8 = *(const ushort8*)(p + i * 8);
#pragma unroll
        for (int j = 0; j < 8; j++) sum += bf2f(v8[j]);
    }
    red[t] = sum;
    __syncthreads();
    if (part == 0)
        vmean[hb * 64 + d] = (red[t] + red[t + 1] + red[t + 2] + red[t + 3]) * (1.0f / 1024.0f);
}

// ---------------- flash attention, split-KV, swapped QK^T + LDS staging ----------
// grid (40, 64): idx -> (qt, chunk); chunk covers KV tiles [4c, min(4c+4, qt+1)).
// K/V double-buffered via global_load_lds (pre-swizzled source), counted vmcnt(4).
// In-register row softmax: lane c owns q=q0+c (S^T = mfma(K,Q)), 2 shfl per tile.
// Defer-max (T13, THR=8 log2); setprio(1) around MFMA clusters (T5).
__global__ __launch_bounds__(256) void k_attn(
    const unsigned short* __restrict__ qh, const unsigned short* __restrict__ kh,
    const unsigned short* __restrict__ vt, const int* __restrict__ mask,
    const float* __restrict__ vmean, float* __restrict__ out,
    char* __restrict__ part) {
    __shared__ unsigned short sK[2][64 * 64];
    __shared__ unsigned short sV[2][64 * 64];   // V^T tiles: [d][kv]
    __shared__ unsigned short sP[4 * 16 * 64];  // per-wave 16q x 64kv P tile

    const int idx = blockIdx.x, hb = blockIdx.y;
    int qt, ch, nch;
    if (idx < 4)       { qt = idx;                 ch = 0;             nch = 1; }
    else if (idx < 12) { qt = 4 + ((idx - 4) >> 1);  ch = (idx - 4) & 1;  nch = 2; }
    else if (idx < 24) { int r = idx - 12; qt = 8 + r / 3; ch = r % 3;   nch = 3; }
    else               { qt = 12 + ((idx - 24) >> 2); ch = (idx - 24) & 3; nch = 4; }
    const int t0 = ch * 4;
    const int t1 = min(t0 + 4, qt + 1);

    const int tid = threadIdx.x;
    const int w = tid >> 6, lane = tid & 63;
    const int c = lane & 15, g = lane >> 4, g4 = g * 4;
    const int q0 = qt * 64 + w * 16;
    const int qg = q0 + c;                        // this lane's q row
    const size_t hboff = (size_t)hb * 65536;
    const int* mp = mask + hb * 1024;
    unsigned short* pw = sP + w * 1024;

    bf16x8 aq[2];
#pragma unroll
    for (int kk = 0; kk < 2; kk++)
        aq[kk] = *(const bf16x8*)(qh + hboff + (size_t)qg * 64 + kk * 32 + g * 8);

    f32x4 oacc[4] = {};
    float lsum = 0.f, mrow = -1e30f;

    const int srow = tid >> 3, sch = tid & 7;
    const int ssc = (sch ^ (srow & 7)) * 8;          // pre-swizzled source col

    auto stage = [&](int t, int buf) {
        const int kv0 = t * 64;
#pragma unroll
        for (int i = 0; i < 2; i++) {
            const int row = i * 32 + srow;
            gload_lds16(kh + hboff + (size_t)(kv0 + row) * 64 + ssc,
                        (char*)sK[buf] + row * 128 + sch * 16);
        }
#pragma unroll
        for (int i = 0; i < 2; i++) {
            const int row = i * 32 + srow;               // row = d
            gload_lds16(vt + hboff + (size_t)row * 1024 + kv0 + ssc,
                        (char*)sV[buf] + row * 128 + sch * 16);
        }
    };

    stage(t0, 0);
    for (int t = t0; t < t1; t++) {
        const int cur = (t - t0) & 1;
        if (t + 1 < t1) {
            stage(t + 1, cur ^ 1);
            asm volatile("s_waitcnt vmcnt(4)" ::: "memory");   // tile t's 4 loads done
        } else {
            asm volatile("s_waitcnt vmcnt(0)" ::: "memory");
        }
        __builtin_amdgcn_s_barrier();
        __builtin_amdgcn_sched_barrier(0);

        const int kv0 = t * 64;
        const bool diag = (t == qt);
        const unsigned short* sKc = sK[cur];
        const unsigned short* sVc = sV[cur];

        // S^T = K Q^T : sacc[ns][r] = S[kv0+ns*16+g4+r][q0+c]
        f32x4 sacc[4] = {};
        __builtin_amdgcn_s_setprio(1);
#pragma unroll
        for (int ns = 0; ns < 4; ns++)
#pragma unroll
            for (int kk = 0; kk < 2; kk++) {
                const bf16x8 bk = *(const bf16x8*)((char*)sKc +
                                    swz((ns * 16 + c) * 128 + kk * 64 + g * 16));
                sacc[ns] = __builtin_amdgcn_mfma_f32_16x16x32_bf16(bk, aq[kk], sacc[ns], 0, 0, 0);
            }
        __builtin_amdgcn_s_setprio(0);

        // mask + causal (per-lane registers)
        float sv[4][4];
        float mx = -1e30f;
#pragma unroll
        for (int ns = 0; ns < 4; ns++) {
            const i32x4 mm = *(const i32x4*)(mp + kv0 + ns * 16 + g4);
#pragma unroll
            for (int r = 0; r < 4; r++) {
                float s = (mm[r] != 0) ? sacc[ns][r] : -1e30f;
                if (diag) s = (kv0 + ns * 16 + g4 + r <= qg) ? s : -1e30f;
                sv[ns][r] = s;
                mx = fmaxf(mx, s);
            }
        }
        // row reduce across g-groups (lanes c, c+16, c+32, c+48)
        mx = fmaxf(mx, __shfl_xor(mx, 16, 64));
        mx = fmaxf(mx, __shfl_xor(mx, 32, 64));

        // defer-max: only rescale when some row's max grew past mrow + 8
        if (!__all(mx - mrow <= 8.0f)) {
            const float mnew = fmaxf(mrow, mx);
            const float alpha = exp2f(mrow - mnew);
            mrow = mnew;
            lsum *= alpha;
            float av[4];
#pragma unroll
            for (int r = 0; r < 4; r++) av[r] = __shfl(alpha, g4 + r, 16);
#pragma unroll
            for (int nd = 0; nd < 4; nd++)
#pragma unroll
                for (int r = 0; r < 4; r++) oacc[nd][r] *= av[r];
        }

        float rs = 0.f;
        u32x2 pk[4];
#pragma unroll
        for (int ns = 0; ns < 4; ns++) {
            const float e0 = exp2f(sv[ns][0] - mrow);
            const float e1 = exp2f(sv[ns][1] - mrow);
            const float e2 = exp2f(sv[ns][2] - mrow);
            const float e3 = exp2f(sv[ns][3] - mrow);
            rs += (e0 + e1) + (e2 + e3);
            pk[ns][0] = cvt_pk_bf16(e0, e1);
            pk[ns][1] = cvt_pk_bf16(e2, e3);
        }
        rs += __shfl_xor(rs, 16, 64);
        rs += __shfl_xor(rs, 32, 64);
        lsum += rs;

        // write P^T fragment -> sP[q=c][kv], 8B per ns
#pragma unroll
        for (int ns = 0; ns < 4; ns++)
            *(u32x2*)((char*)pw + swz(c * 128 + (ns * 16 + g4) * 2)) = pk[ns];

        asm volatile("s_waitcnt lgkmcnt(0)" ::: "memory");
        // O += P V  (A = P rows q=c from sP, B = V^T frags from sV)
        __builtin_amdgcn_s_setprio(1);
#pragma unroll
        for (int ks = 0; ks < 2; ks++) {
            const bf16x8 ap = *(const bf16x8*)((char*)pw + swz(c * 128 + ks * 64 + g * 16));
#pragma unroll
            for (int nd = 0; nd < 4; nd++) {
                const bf16x8 bvv = *(const bf16x8*)((char*)sVc +
                                     swz((nd * 16 + c) * 128 + ks * 64 + g * 16));
                oacc[nd] = __builtin_amdgcn_mfma_f32_16x16x32_bf16(ap, bvv, oacc[nd], 0, 0, 0);
            }
        }
        __builtin_amdgcn_s_setprio(0);
        __builtin_amdgcn_sched_barrier(0);
        __builtin_amdgcn_s_barrier();      // LDS reads done before next stage overwrites
        __builtin_amdgcn_sched_barrier(0);
    }

    if (nch == 1) {
        const int bidx = hb & 3, head = hb >> 2;
        float lf[4], mf[4];
#pragma unroll
        for (int r = 0; r < 4; r++) {
            lf[r] = __shfl(lsum, g4 + r, 16);
            mf[r] = __shfl(mrow, g4 + r, 16);
        }
#pragma unroll
        for (int nd = 0; nd < 4; nd++)
#pragma unroll
            for (int r = 0; r < 4; r++) {
                const int s = q0 + g4 + r;
                const int dcol = nd * 16 + c;
                const float val = (mf[r] < -5e29f) ? vmean[hb * 64 + dcol]
                                                   : oacc[nd][r] / lf[r];
                out[(size_t)bidx * 1048576 + (size_t)s * 1024 + head * 64 + dcol] = val;
            }
    } else {
        // partial: bf16 O~ [64][64] + f32 m[64] + f32 l[64]  (slot = idx-4)
        char* sp = part + ((size_t)hb * 36 + (idx - 4)) * 8704;
        unsigned short* op = (unsigned short*)sp;
#pragma unroll
        for (int nd = 0; nd < 4; nd++)
#pragma unroll
            for (int r = 0; r < 4; r++)
                op[(w * 16 + g4 + r) * 64 + nd * 16 + c] = f2bf(oacc[nd][r]);
        if (g == 0) {   // lanes 0-15 hold m/l for q = w*16 + c
            float* mo = (float*)(sp + 8192);
            float* lo = (float*)(sp + 8448);
            mo[w * 16 + c] = mrow;
            lo[w * 16 + c] = lsum;
        }
    }
}

// ---------------- combine partials for qt >= 4 ----------------
__global__ __launch_bounds__(256) void k_combine(
    const char* __restrict__ part, const float* __restrict__ vmean,
    float* __restrict__ out) {
    const int qt = 4 + blockIdx.x, hb = blockIdx.y;
    int nch, base;
    if (qt < 8)       { nch = 2; base = (qt - 4) * 2; }
    else if (qt < 12) { nch = 3; base = 8 + (qt - 8) * 3; }
    else              { nch = 4; base = 20 + (qt - 12) * 4; }
    const int t = threadIdx.x;
    const int row = t >> 2, d0 = (t & 3) * 16;
    const char* sp0 = part + ((size_t)hb * 36 + base) * 8704;

    float mi[4], li[4];
    float m = -1e30f;
#pragma unroll
    for (int i = 0; i < 4; i++)
        if (i < nch) {
            const char* sp = sp0 + (size_t)i * 8704;
            mi[i] = ((const float*)(sp + 8192))[row];
            li[i] = ((const float*)(sp + 8448))[row];
            m = fmaxf(m, mi[i]);
        }
    float L = 0.f;
    float o[16];
#pragma unroll
    for (int j = 0; j < 16; j++) o[j] = 0.f;
#pragma unroll
    for (int i = 0; i < 4; i++)
        if (i < nch) {
            const float wgt = exp2f(mi[i] - m);
            L += wgt * li[i];
            const unsigned short* op =
                (const unsigned short*)(sp0 + (size_t)i * 8704) + row * 64 + d0;
            ushort8 a = *(const ushort8*)op;
            ushort8 b = *(const ushort8*)(op + 8);
#pragma unroll
            for (int j = 0; j < 8; j++) {
                o[j]     += wgt * bf2f(a[j]);
                o[8 + j] += wgt * bf2f(b[j]);
            }
        }
    const int bidx = hb & 3, head = hb >> 2;
    float* dst = out + (size_t)bidx * 1048576 + (size_t)(qt * 64 + row) * 1024 + head * 64 + d0;
    if (m > -5e29f) {   // fully-masked rows keep m=-1e30 -> uniform-softmax fallback
        const float inv = 1.0f / L;
#pragma unroll
        for (int j = 0; j < 16; j++) dst[j] = o[j] * inv;
    } else {
#pragma unroll
        for (int j = 0; j < 16; j++) dst[j] = vmean[hb * 64 + d0 + j];
    }
}

extern "C" void kernel_launch(void* const* d_in, const int* in_sizes, int n_in,
                              void* d_out, int out_size, void* d_ws, size_t ws_size,
                              hipStream_t stream) {
    const float* q  = (const float*)d_in[0];
    const float* k  = (const float*)d_in[1];
    const float* v  = (const float*)d_in[2];
    const int* mask = (const int*)d_in[3];
    const float* Wq = (const float*)d_in[4];
    const float* bq = (const float*)d_in[5];
    const float* Wk = (const float*)d_in[6];
    const float* bk = (const float*)d_in[7];
    const float* Wv = (const float*)d_in[8];
    const float* bv = (const float*)d_in[9];
    float* out = (float*)d_out;

    unsigned short* qb = (unsigned short*)d_ws;
    unsigned short* kb = qb + 4194304;
    unsigned short* vb = kb + 4194304;
    unsigned short* wt = vb + 4194304;     // 3 * 1048576
    unsigned short* qh = wt + 3 * 1048576;
    unsigned short* kh = qh + 4194304;
    unsigned short* vh = kh + 4194304;     // unused (kept for layout stability)
    unsigned short* vt = vh + 4194304;
    float* vmean = (float*)(vt + 4194304); // 64*64 floats
    char* part = (char*)qb;                // 20.1 MB, aliases qb/kb/vb (dead after k_proj)

    k_prep<<<dim3(2304, 1, 3), 256, 0, stream>>>(q, k, v, Wq, Wk, Wv, qb, kb, vb, wt);
    k_proj<<<dim3(256, 1, 3), 512, 0, stream>>>(qb, kb, vb, wt, bq, bk, bv, qh, kh, vt);
    k_vmean<<<64, 256, 0, stream>>>(vt, vmean);
    k_attn<<<dim3(40, 64), 256, 0, stream>>>(qh, kh, vt, mask, vmean, out, part);
    k_combine<<<dim3(12, 64), 256, 0, stream>>>(part, vmean, out);
}